// Round 1
// baseline (629.516 us; speedup 1.0000x reference)
//
#include <hip/hip_runtime.h>
#include <cstdint>
#include <cstddef>

// Problem constants (FusedExperts: E=8 TOPK=2, B=2 S=4096 D=1024 H=2048)
#define TT   8192     // tokens = B*S
#define DD   1024     // model dim
#define HH   2048     // hidden dim
#define H2   4096     // 2*H
#define EE   8        // experts
#define PP   16384    // routed pairs = TT*TOPK
#define PADROWS 17280 // max sum of per-expert 128-padded group sizes = 135*128
#define MAXTILES 135

typedef unsigned short u16;
typedef __attribute__((ext_vector_type(8))) short bf16x8;   // 8 bf16 = 4 VGPR (MFMA A/B frag)
typedef __attribute__((ext_vector_type(8))) unsigned short u16x8;
typedef __attribute__((ext_vector_type(4))) float f32x4;    // MFMA C/D frag

__device__ __forceinline__ u16 f2bf(float f) {
  unsigned int u = __builtin_bit_cast(unsigned int, f);
  u += 0x7fffu + ((u >> 16) & 1u);          // round-to-nearest-even
  return (u16)(u >> 16);
}
__device__ __forceinline__ float bf2f(u16 s) {
  unsigned int u = ((unsigned int)s) << 16;
  return __builtin_bit_cast(float, u);
}

__device__ __forceinline__ void gload_lds16(const u16* g, u16* l) {
  __builtin_amdgcn_global_load_lds(
      (const __attribute__((address_space(1))) void*)g,
      (__attribute__((address_space(3))) void*)l, 16, 0, 0);
}

// ---------------- casts ----------------
__global__ void cast_x_kernel(const float* __restrict__ x, u16* __restrict__ xb) {
  const long i = (long)blockIdx.x * 256 + threadIdx.x;  // one thread -> 8 elems
  const f32x4* s = (const f32x4*)(x + i * 8);
  f32x4 a = s[0], b = s[1];
  u16x8 o;
  o[0]=f2bf(a[0]); o[1]=f2bf(a[1]); o[2]=f2bf(a[2]); o[3]=f2bf(a[3]);
  o[4]=f2bf(b[0]); o[5]=f2bf(b[1]); o[6]=f2bf(b[2]); o[7]=f2bf(b[3]);
  *(u16x8*)(xb + i * 8) = o;
}

// src [E][R][C] f32  ->  dst [E][C][R] bf16 (per-expert transpose)
__global__ void tcast_kernel(const float* __restrict__ src, u16* __restrict__ dst,
                             int R, int C) {
  __shared__ u16 tile[32][34];
  const long base = (long)blockIdx.z * R * C;
  const int c0 = blockIdx.x * 32, r0v = blockIdx.y * 32;
  const int tx = threadIdx.x, ty = threadIdx.y;
#pragma unroll
  for (int rr = 0; rr < 4; ++rr) {
    int r = ty + rr * 8;
    tile[r][tx] = f2bf(src[base + (long)(r0v + r) * C + c0 + tx]);
  }
  __syncthreads();
#pragma unroll
  for (int rr = 0; rr < 4; ++rr) {
    int c = ty + rr * 8;
    dst[base + (long)(c0 + c) * R + r0v + tx] = tile[tx][c];
  }
}

// ---------------- routing ----------------
__global__ void count_kernel(const int* __restrict__ eidx, int* __restrict__ cnt) {
  int i = blockIdx.x * 256 + threadIdx.x;
  if (i < PP) atomicAdd(&cnt[eidx[i]], 1);
}
__global__ void scan_kernel(const int* __restrict__ cnt, int* __restrict__ pofs) {
  if (threadIdx.x == 0 && blockIdx.x == 0) {
    int run = 0;
    for (int e = 0; e < EE; ++e) { pofs[e] = run; run += ((cnt[e] + 127) >> 7) << 7; }
    pofs[EE] = run;
  }
}
__global__ void place_kernel(const int* __restrict__ eidx, const float* __restrict__ p,
                             const int* __restrict__ pofs, int* __restrict__ cnt2,
                             int* __restrict__ ptok, float* __restrict__ pscale,
                             int* __restrict__ ppos) {
  int i = blockIdx.x * 256 + threadIdx.x;
  if (i < PP) {
    int e = eidx[i];
    int r = atomicAdd(&cnt2[e], 1);
    int pos = pofs[e] + r;
    ptok[pos] = i >> 1;       // token index (TOPK=2)
    pscale[pos] = p[i];
    ppos[i] = pos;
  }
}

// ---------------- GEMM1: hb[pos, 0:H] = silu(g)*h,  hg = x[tok] @ w13[e] ----------------
// tile: 128 rows x (64 h-cols + 64 g-cols), BK=32. 4 waves, each 32 rows x 128 local cols.
__global__ __launch_bounds__(256, 2)
void gemm1_kernel(const u16* __restrict__ xb, const u16* __restrict__ w13t,
                  const int* __restrict__ ptok, const int* __restrict__ pofs,
                  u16* __restrict__ hb) {
  __shared__ __align__(16) u16 lds_a[128 * 32];
  __shared__ __align__(16) u16 lds_b[128 * 32];

  const int ts = blockIdx.x * 128;
  if (ts >= pofs[EE]) return;
  int e = 0;
#pragma unroll
  for (int i = 1; i < EE; ++i) e += (ts >= pofs[i]) ? 1 : 0;

  const int j = blockIdx.y;              // 0..31: h cols [j*64, j*64+64), g = +HH
  const int tid = threadIdx.x;
  const int w = tid >> 6, lane = tid & 63;

  const int r0 = tid >> 2;               // staged row 0..63 (round 0); +64 round 1
  const int kk = (tid & 3) * 8;          // k element offset within BK

  const long tok0 = ptok[ts + r0];
  const long tok1 = ptok[ts + 64 + r0];
  const u16* asrc0 = xb + tok0 * DD + kk;
  const u16* asrc1 = xb + tok1 * DD + kk;
  const u16* bbase = w13t + (long)e * ((long)H2 * DD);
  const u16* bsrc0 = bbase + (long)(j * 64 + r0) * DD + kk;        // h col
  const u16* bsrc1 = bbase + (long)(HH + j * 64 + r0) * DD + kk;   // g col

  u16* lA0 = lds_a + w * 512;            // wave-uniform LDS bases (lane*16B added by HW)
  u16* lA1 = lds_a + 2048 + w * 512;
  u16* lB0 = lds_b + w * 512;
  u16* lB1 = lds_b + 2048 + w * 512;

  f32x4 acc[2][8];
#pragma unroll
  for (int m = 0; m < 2; ++m)
#pragma unroll
    for (int n = 0; n < 8; ++n) acc[m][n] = (f32x4){0.f, 0.f, 0.f, 0.f};

  const int aoff = (w * 32 + (lane & 15)) * 32 + (lane >> 4) * 8;  // u16 units
  const int boff = (lane & 15) * 32 + (lane >> 4) * 8;

  for (int k0 = 0; k0 < DD; k0 += 32) {
    gload_lds16(asrc0, lA0);
    gload_lds16(asrc1, lA1);
    gload_lds16(bsrc0, lB0);
    gload_lds16(bsrc1, lB1);
    asrc0 += 32; asrc1 += 32; bsrc0 += 32; bsrc1 += 32;
    __syncthreads();

    bf16x8 af[2], bfr[8];
#pragma unroll
    for (int m = 0; m < 2; ++m) af[m] = *(const bf16x8*)(lds_a + aoff + m * 16 * 32);
#pragma unroll
    for (int n = 0; n < 8; ++n) bfr[n] = *(const bf16x8*)(lds_b + boff + n * 16 * 32);
#pragma unroll
    for (int m = 0; m < 2; ++m)
#pragma unroll
      for (int n = 0; n < 8; ++n)
        acc[m][n] = __builtin_amdgcn_mfma_f32_16x16x32_bf16(af[m], bfr[n], acc[m][n], 0, 0, 0);
    __syncthreads();
  }

  // epilogue: silu(g)*h entirely in registers (frag n -> h, n+4 -> g, same lane/col)
  const int orow0 = ts + w * 32 + ((lane >> 4) << 2);
  const int ocol0 = j * 64 + (lane & 15);
#pragma unroll
  for (int m = 0; m < 2; ++m)
#pragma unroll
    for (int n = 0; n < 4; ++n)
#pragma unroll
      for (int r = 0; r < 4; ++r) {
        float h = acc[m][n][r];
        float g = acc[m][n + 4][r];
        float v = h * (g / (1.f + __expf(-g)));
        hb[(long)(orow0 + m * 16 + r) * HH + (ocol0 + n * 16)] = f2bf(v);
      }
}

// ---------------- GEMM2: ye[pos,:] = scale * (hb[pos,:] @ w2[e]) ----------------
__global__ __launch_bounds__(256, 2)
void gemm2_kernel(const u16* __restrict__ hb, const u16* __restrict__ w2t,
                  const float* __restrict__ pscale, const int* __restrict__ pofs,
                  u16* __restrict__ ye) {
  __shared__ __align__(16) u16 lds_a[128 * 32];
  __shared__ __align__(16) u16 lds_b[128 * 32];

  const int ts = blockIdx.x * 128;
  if (ts >= pofs[EE]) return;
  int e = 0;
#pragma unroll
  for (int i = 1; i < EE; ++i) e += (ts >= pofs[i]) ? 1 : 0;

  const int j = blockIdx.y;              // 0..7: out cols [j*128, j*128+128)
  const int tid = threadIdx.x;
  const int w = tid >> 6, lane = tid & 63;
  const int r0 = tid >> 2;
  const int kk = (tid & 3) * 8;

  const u16* asrc0 = hb + (long)(ts + r0) * HH + kk;
  const u16* asrc1 = hb + (long)(ts + 64 + r0) * HH + kk;
  const u16* bbase = w2t + (long)e * ((long)DD * HH);
  const u16* bsrc0 = bbase + (long)(j * 128 + r0) * HH + kk;
  const u16* bsrc1 = bbase + (long)(j * 128 + 64 + r0) * HH + kk;

  u16* lA0 = lds_a + w * 512;
  u16* lA1 = lds_a + 2048 + w * 512;
  u16* lB0 = lds_b + w * 512;
  u16* lB1 = lds_b + 2048 + w * 512;

  f32x4 acc[2][8];
#pragma unroll
  for (int m = 0; m < 2; ++m)
#pragma unroll
    for (int n = 0; n < 8; ++n) acc[m][n] = (f32x4){0.f, 0.f, 0.f, 0.f};

  const int aoff = (w * 32 + (lane & 15)) * 32 + (lane >> 4) * 8;
  const int boff = (lane & 15) * 32 + (lane >> 4) * 8;

  for (int k0 = 0; k0 < HH; k0 += 32) {
    gload_lds16(asrc0, lA0);
    gload_lds16(asrc1, lA1);
    gload_lds16(bsrc0, lB0);
    gload_lds16(bsrc1, lB1);
    asrc0 += 32; asrc1 += 32; bsrc0 += 32; bsrc1 += 32;
    __syncthreads();

    bf16x8 af[2], bfr[8];
#pragma unroll
    for (int m = 0; m < 2; ++m) af[m] = *(const bf16x8*)(lds_a + aoff + m * 16 * 32);
#pragma unroll
    for (int n = 0; n < 8; ++n) bfr[n] = *(const bf16x8*)(lds_b + boff + n * 16 * 32);
#pragma unroll
    for (int m = 0; m < 2; ++m)
#pragma unroll
      for (int n = 0; n < 8; ++n)
        acc[m][n] = __builtin_amdgcn_mfma_f32_16x16x32_bf16(af[m], bfr[n], acc[m][n], 0, 0, 0);
    __syncthreads();
  }

  const int orow0 = ts + w * 32 + ((lane >> 4) << 2);
  const int ocol0 = j * 128 + (lane & 15);
#pragma unroll
  for (int m = 0; m < 2; ++m)
#pragma unroll
    for (int r = 0; r < 4; ++r) {
      const int row = orow0 + m * 16 + r;
      const float sc = pscale[row];   // 0.0 for pad rows -> ye pad rows = 0
#pragma unroll
      for (int n = 0; n < 8; ++n)
        ye[(long)row * DD + (ocol0 + n * 16)] = f2bf(acc[m][n][r] * sc);
    }
}

// ---------------- combine: y[t] = ye[pos0] + ye[pos1] ----------------
__global__ void combine_kernel(const u16* __restrict__ ye, const int* __restrict__ ppos,
                               float* __restrict__ y) {
  const long i = (long)blockIdx.x * 256 + threadIdx.x;  // one thread -> 8 outputs
  const int t = (int)(i >> 7);
  const int c = ((int)i & 127) * 8;
  const int p0 = ppos[t * 2], p1 = ppos[t * 2 + 1];
  u16x8 v0 = *(const u16x8*)(ye + (long)p0 * DD + c);
  u16x8 v1 = *(const u16x8*)(ye + (long)p1 * DD + c);
  f32x4 o0, o1;
  o0[0] = bf2f(v0[0]) + bf2f(v1[0]);
  o0[1] = bf2f(v0[1]) + bf2f(v1[1]);
  o0[2] = bf2f(v0[2]) + bf2f(v1[2]);
  o0[3] = bf2f(v0[3]) + bf2f(v1[3]);
  o1[0] = bf2f(v0[4]) + bf2f(v1[4]);
  o1[1] = bf2f(v0[5]) + bf2f(v1[5]);
  o1[2] = bf2f(v0[6]) + bf2f(v1[6]);
  o1[3] = bf2f(v0[7]) + bf2f(v1[7]);
  *(f32x4*)(y + (long)t * DD + c) = o0;
  *(f32x4*)(y + (long)t * DD + c + 4) = o1;
}

extern "C" void kernel_launch(void* const* d_in, const int* in_sizes, int n_in,
                              void* d_out, int out_size, void* d_ws, size_t ws_size,
                              hipStream_t stream) {
  const float* x    = (const float*)d_in[0];
  const float* ep   = (const float*)d_in[1];
  const int*   eidx = (const int*)d_in[2];
  const float* w13  = (const float*)d_in[3];
  const float* w2   = (const float*)d_in[4];
  float* y = (float*)d_out;

  char* ws = (char*)d_ws;
  size_t off = 0;
  auto alloc = [&](size_t bytes) {
    char* p = ws + off;
    off = (off + bytes + 255) & ~(size_t)255;
    return p;
  };
  u16* xb     = (u16*)alloc((size_t)TT * DD * 2);
  u16* w13t   = (u16*)alloc((size_t)EE * H2 * DD * 2);
  u16* w2t    = (u16*)alloc((size_t)EE * DD * HH * 2);
  u16* hb     = (u16*)alloc((size_t)PADROWS * HH * 2);
  u16* ye     = (u16*)alloc((size_t)PADROWS * DD * 2);
  char* zbase = ws + off;
  int*   ptok   = (int*)alloc((size_t)PADROWS * 4);
  float* pscale = (float*)alloc((size_t)PADROWS * 4);
  int*   cnt    = (int*)alloc(EE * 4);
  int*   cnt2   = (int*)alloc(EE * 4);
  size_t zbytes = (size_t)((ws + off) - zbase);
  int*   pofs   = (int*)alloc((EE + 1) * 4);
  int*   ppos   = (int*)alloc((size_t)PP * 4);
  (void)ws_size; (void)in_sizes; (void)n_in; (void)out_size;

  // zero routing state (pad rows -> token 0, scale 0)
  hipMemsetAsync(zbase, 0, zbytes, stream);

  cast_x_kernel<<<4096, 256, 0, stream>>>(x, xb);
  dim3 tb(32, 8);
  tcast_kernel<<<dim3(H2 / 32, DD / 32, EE), tb, 0, stream>>>(w13, w13t, DD, H2);
  tcast_kernel<<<dim3(DD / 32, HH / 32, EE), tb, 0, stream>>>(w2, w2t, HH, DD);

  count_kernel<<<PP / 256, 256, 0, stream>>>(eidx, cnt);
  scan_kernel<<<1, 64, 0, stream>>>(cnt, pofs);
  place_kernel<<<PP / 256, 256, 0, stream>>>(eidx, ep, pofs, cnt2, ptok, pscale, ppos);

  gemm1_kernel<<<dim3(MAXTILES, H2 / 128), 256, 0, stream>>>(xb, w13t, ptok, pofs, hb);
  gemm2_kernel<<<dim3(MAXTILES, DD / 128), 256, 0, stream>>>(hb, w2t, pscale, pofs, ye);
  combine_kernel<<<4096, 256, 0, stream>>>(ye, ppos, y);
}

// Round 2
// 540.727 us; speedup vs baseline: 1.1642x; 1.1642x over previous
//
#include <hip/hip_runtime.h>
#include <cstdint>
#include <cstddef>

// Problem constants (FusedExperts: E=8 TOPK=2, B=2 S=4096 D=1024 H=2048)
#define TT   8192     // tokens = B*S
#define DD   1024     // model dim
#define HH   2048     // hidden dim
#define H2   4096     // 2*H
#define EE   8        // experts
#define PP   16384    // routed pairs = TT*TOPK
#define PADROWS 17280 // max sum of per-expert 128-padded group sizes = 135*128
#define MAXTILES 135

typedef unsigned short u16;
typedef __attribute__((ext_vector_type(8))) short bf16x8;   // 8 bf16 = 4 VGPR (MFMA A/B frag)
typedef __attribute__((ext_vector_type(8))) unsigned short u16x8;
typedef __attribute__((ext_vector_type(4))) float f32x4;    // MFMA C/D frag

__device__ __forceinline__ u16 f2bf(float f) {
  unsigned int u = __builtin_bit_cast(unsigned int, f);
  u += 0x7fffu + ((u >> 16) & 1u);          // round-to-nearest-even
  return (u16)(u >> 16);
}
__device__ __forceinline__ float bf2f(u16 s) {
  unsigned int u = ((unsigned int)s) << 16;
  return __builtin_bit_cast(float, u);
}

__device__ __forceinline__ void gload_lds16(const u16* g, u16* l) {
  __builtin_amdgcn_global_load_lds(
      (const __attribute__((address_space(1))) void*)g,
      (__attribute__((address_space(3))) void*)l, 16, 0, 0);
}

// ---------------- casts ----------------
__global__ void cast_x_kernel(const float* __restrict__ x, u16* __restrict__ xb) {
  const long i = (long)blockIdx.x * 256 + threadIdx.x;  // one thread -> 8 elems
  const f32x4* s = (const f32x4*)(x + i * 8);
  f32x4 a = s[0], b = s[1];
  u16x8 o;
  o[0]=f2bf(a[0]); o[1]=f2bf(a[1]); o[2]=f2bf(a[2]); o[3]=f2bf(a[3]);
  o[4]=f2bf(b[0]); o[5]=f2bf(b[1]); o[6]=f2bf(b[2]); o[7]=f2bf(b[3]);
  *(u16x8*)(xb + i * 8) = o;
}

// src [E][R][C] f32  ->  dst [E][C][R] bf16 (per-expert transpose)
__global__ void tcast_kernel(const float* __restrict__ src, u16* __restrict__ dst,
                             int R, int C) {
  __shared__ u16 tile[32][34];
  const long base = (long)blockIdx.z * R * C;
  const int c0 = blockIdx.x * 32, r0v = blockIdx.y * 32;
  const int tx = threadIdx.x, ty = threadIdx.y;
#pragma unroll
  for (int rr = 0; rr < 4; ++rr) {
    int r = ty + rr * 8;
    tile[r][tx] = f2bf(src[base + (long)(r0v + r) * C + c0 + tx]);
  }
  __syncthreads();
#pragma unroll
  for (int rr = 0; rr < 4; ++rr) {
    int c = ty + rr * 8;
    dst[base + (long)(c0 + c) * R + r0v + tx] = tile[tx][c];
  }
}

// ---------------- routing ----------------
__global__ void count_kernel(const int* __restrict__ eidx, int* __restrict__ cnt) {
  int i = blockIdx.x * 256 + threadIdx.x;
  if (i < PP) atomicAdd(&cnt[eidx[i]], 1);
}
__global__ void scan_kernel(const int* __restrict__ cnt, int* __restrict__ pofs) {
  if (threadIdx.x == 0 && blockIdx.x == 0) {
    int run = 0;
    for (int e = 0; e < EE; ++e) { pofs[e] = run; run += ((cnt[e] + 127) >> 7) << 7; }
    pofs[EE] = run;
  }
}
__global__ void place_kernel(const int* __restrict__ eidx, const float* __restrict__ p,
                             const int* __restrict__ pofs, int* __restrict__ cnt2,
                             int* __restrict__ ptok, float* __restrict__ pscale,
                             int* __restrict__ ppos) {
  int i = blockIdx.x * 256 + threadIdx.x;
  if (i < PP) {
    int e = eidx[i];
    int r = atomicAdd(&cnt2[e], 1);
    int pos = pofs[e] + r;
    ptok[pos] = i >> 1;       // token index (TOPK=2)
    pscale[pos] = p[i];
    ppos[i] = pos;
  }
}

// ============ GEMM cores: m97 structure + T2 XOR swizzle ============
// LDS tile [128][64] bf16 (128 B rows, 8 slots of 16 B). Data for (row, slot)
// stored at slot' = slot ^ (row&7)  -> ds_read_b128 groups hit all 32 banks.
// global_load_lds writes linearly, so the per-lane GLOBAL source is
// inverse-swizzled (rule #21). 4 waves 2x2, each wave 4x4 16x16x32 frags.

// GEMM1: hb[pos, 0:H] = silu(g)*h where hg = x[tok] @ w13[e]
// Block: 128 rows x (64 h-cols + 64 g-cols). Wave n-frags: n0,1 = h, n2,3 = g.
__global__ __launch_bounds__(256, 2)
void gemm1_kernel(const u16* __restrict__ xb, const u16* __restrict__ w13t,
                  const int* __restrict__ ptok, const int* __restrict__ pofs,
                  u16* __restrict__ hb) {
  __shared__ __align__(16) u16 lds_a[128 * 64];
  __shared__ __align__(16) u16 lds_b[128 * 64];

  const int ts = blockIdx.x * 128;
  if (ts >= pofs[EE]) return;
  int e = 0;
#pragma unroll
  for (int i = 1; i < EE; ++i) e += (ts >= pofs[i]) ? 1 : 0;

  const int j = blockIdx.y;              // h cols [j*64, j*64+64)
  const int tid = threadIdx.x;
  const int w = tid >> 6, lane = tid & 63;
  const int wr = w >> 1, wc = w & 1;

  const u16* bbase = w13t + (long)e * ((long)H2 * DD);

  // --- staging setup: 4 rounds each of A and B; 16 B per lane per round ---
  const u16* asrc[4]; const u16* bsrc[4];
  u16* adst[4]; u16* bdst[4];
#pragma unroll
  for (int r = 0; r < 4; ++r) {
    const int L = (r * 4 + w) * 1024 + lane * 16;       // linear LDS byte
    const int row = L >> 7;                              // 128 B per row
    const int slot = ((L >> 4) & 7) ^ (row & 7);         // inverse-swizzled src slot
    asrc[r] = xb + (long)ptok[ts + row] * DD + slot * 8;
    const int gr = (row < 64) ? (j * 64 + row) : (HH + j * 64 + row - 64);
    bsrc[r] = bbase + (long)gr * DD + slot * 8;
    adst[r] = lds_a + (r * 4 + w) * 512;                 // wave-uniform base
    bdst[r] = lds_b + (r * 4 + w) * 512;
  }

  // --- fragment read offsets (u16 units), swizzled ---
  const int rA = wr * 64 + (lane & 15);
  const int sA = lane >> 4;
  const int x7 = lane & 7;
  int aoff[2][4], boff[2][4];
  int rB[4];
  rB[0] = wc * 32 + (lane & 15);
  rB[1] = wc * 32 + 16 + (lane & 15);
  rB[2] = 64 + wc * 32 + (lane & 15);
  rB[3] = 64 + wc * 32 + 16 + (lane & 15);
#pragma unroll
  for (int kk = 0; kk < 2; ++kk) {
    const int sl = ((kk * 4 + sA) ^ x7) * 8;
#pragma unroll
    for (int m = 0; m < 4; ++m) aoff[kk][m] = (rA + m * 16) * 64 + sl;
#pragma unroll
    for (int n = 0; n < 4; ++n) boff[kk][n] = rB[n] * 64 + sl;
  }

  f32x4 acc[4][4];
#pragma unroll
  for (int m = 0; m < 4; ++m)
#pragma unroll
    for (int n = 0; n < 4; ++n) acc[m][n] = (f32x4){0.f, 0.f, 0.f, 0.f};

  for (int k0 = 0; k0 < DD; k0 += 64) {
#pragma unroll
    for (int r = 0; r < 4; ++r) gload_lds16(asrc[r] + k0, adst[r]);
#pragma unroll
    for (int r = 0; r < 4; ++r) gload_lds16(bsrc[r] + k0, bdst[r]);
    __syncthreads();

    bf16x8 af[2][4], bfr[2][4];
#pragma unroll
    for (int kk = 0; kk < 2; ++kk) {
#pragma unroll
      for (int m = 0; m < 4; ++m) af[kk][m] = *(const bf16x8*)(lds_a + aoff[kk][m]);
#pragma unroll
      for (int n = 0; n < 4; ++n) bfr[kk][n] = *(const bf16x8*)(lds_b + boff[kk][n]);
    }
#pragma unroll
    for (int m = 0; m < 4; ++m)
#pragma unroll
      for (int n = 0; n < 4; ++n)
#pragma unroll
        for (int kk = 0; kk < 2; ++kk)
          acc[m][n] = __builtin_amdgcn_mfma_f32_16x16x32_bf16(af[kk][m], bfr[kk][n], acc[m][n], 0, 0, 0);
    __syncthreads();
  }

  // epilogue: silu(g)*h in registers (n-frag pairs (0,2) and (1,3) share cols)
  const int rg = lane >> 4;              // C/D: row = rg*4 + r, col = lane&15
#pragma unroll
  for (int m = 0; m < 4; ++m)
#pragma unroll
    for (int n = 0; n < 2; ++n) {
      const int col = j * 64 + wc * 32 + n * 16 + (lane & 15);
#pragma unroll
      for (int r = 0; r < 4; ++r) {
        const int row = ts + wr * 64 + m * 16 + rg * 4 + r;
        const float h = acc[m][n][r];
        const float g = acc[m][n + 2][r];
        hb[(long)row * HH + col] = f2bf(h * (g / (1.f + __expf(-g))));
      }
    }
}

// GEMM2: ye[pos,:] = pscale[pos] * (hb[pos,:] @ w2t[e]^T), tile 128x128
__global__ __launch_bounds__(256, 2)
void gemm2_kernel(const u16* __restrict__ hb, const u16* __restrict__ w2t,
                  const float* __restrict__ pscale, const int* __restrict__ pofs,
                  u16* __restrict__ ye) {
  __shared__ __align__(16) u16 lds_a[128 * 64];
  __shared__ __align__(16) u16 lds_b[128 * 64];

  const int ts = blockIdx.x * 128;
  if (ts >= pofs[EE]) return;
  int e = 0;
#pragma unroll
  for (int i = 1; i < EE; ++i) e += (ts >= pofs[i]) ? 1 : 0;

  const int j = blockIdx.y;              // out cols [j*128, j*128+128)
  const int tid = threadIdx.x;
  const int w = tid >> 6, lane = tid & 63;
  const int wr = w >> 1, wc = w & 1;

  const u16* bbase = w2t + (long)e * ((long)DD * HH);

  const u16* asrc[4]; const u16* bsrc[4];
  u16* adst[4]; u16* bdst[4];
#pragma unroll
  for (int r = 0; r < 4; ++r) {
    const int L = (r * 4 + w) * 1024 + lane * 16;
    const int row = L >> 7;
    const int slot = ((L >> 4) & 7) ^ (row & 7);
    asrc[r] = hb + (long)(ts + row) * HH + slot * 8;
    bsrc[r] = bbase + (long)(j * 128 + row) * HH + slot * 8;
    adst[r] = lds_a + (r * 4 + w) * 512;
    bdst[r] = lds_b + (r * 4 + w) * 512;
  }

  const int rA = wr * 64 + (lane & 15);
  const int sA = lane >> 4;
  const int x7 = lane & 7;
  int aoff[2][4], boff[2][4];
#pragma unroll
  for (int kk = 0; kk < 2; ++kk) {
    const int sl = ((kk * 4 + sA) ^ x7) * 8;
#pragma unroll
    for (int m = 0; m < 4; ++m) aoff[kk][m] = (rA + m * 16) * 64 + sl;
#pragma unroll
    for (int n = 0; n < 4; ++n) boff[kk][n] = (wc * 64 + n * 16 + (lane & 15)) * 64 + sl;
  }

  f32x4 acc[4][4];
#pragma unroll
  for (int m = 0; m < 4; ++m)
#pragma unroll
    for (int n = 0; n < 4; ++n) acc[m][n] = (f32x4){0.f, 0.f, 0.f, 0.f};

  for (int k0 = 0; k0 < HH; k0 += 64) {
#pragma unroll
    for (int r = 0; r < 4; ++r) gload_lds16(asrc[r] + k0, adst[r]);
#pragma unroll
    for (int r = 0; r < 4; ++r) gload_lds16(bsrc[r] + k0, bdst[r]);
    __syncthreads();

    bf16x8 af[2][4], bfr[2][4];
#pragma unroll
    for (int kk = 0; kk < 2; ++kk) {
#pragma unroll
      for (int m = 0; m < 4; ++m) af[kk][m] = *(const bf16x8*)(lds_a + aoff[kk][m]);
#pragma unroll
      for (int n = 0; n < 4; ++n) bfr[kk][n] = *(const bf16x8*)(lds_b + boff[kk][n]);
    }
#pragma unroll
    for (int m = 0; m < 4; ++m)
#pragma unroll
      for (int n = 0; n < 4; ++n)
#pragma unroll
        for (int kk = 0; kk < 2; ++kk)
          acc[m][n] = __builtin_amdgcn_mfma_f32_16x16x32_bf16(af[kk][m], bfr[kk][n], acc[m][n], 0, 0, 0);
    __syncthreads();
  }

  const int rg = lane >> 4;
#pragma unroll
  for (int m = 0; m < 4; ++m)
#pragma unroll
    for (int r = 0; r < 4; ++r) {
      const int row = ts + wr * 64 + m * 16 + rg * 4 + r;
      const float sc = pscale[row];   // 0.0 for pad rows
#pragma unroll
      for (int n = 0; n < 4; ++n) {
        const int col = j * 128 + wc * 64 + n * 16 + (lane & 15);
        ye[(long)row * DD + col] = f2bf(acc[m][n][r] * sc);
      }
    }
}

// ---------------- combine: y[t] = ye[pos0] + ye[pos1] ----------------
__global__ void combine_kernel(const u16* __restrict__ ye, const int* __restrict__ ppos,
                               float* __restrict__ y) {
  const long i = (long)blockIdx.x * 256 + threadIdx.x;  // one thread -> 8 outputs
  const int t = (int)(i >> 7);
  const int c = ((int)i & 127) * 8;
  const int p0 = ppos[t * 2], p1 = ppos[t * 2 + 1];
  u16x8 v0 = *(const u16x8*)(ye + (long)p0 * DD + c);
  u16x8 v1 = *(const u16x8*)(ye + (long)p1 * DD + c);
  f32x4 o0, o1;
  o0[0] = bf2f(v0[0]) + bf2f(v1[0]);
  o0[1] = bf2f(v0[1]) + bf2f(v1[1]);
  o0[2] = bf2f(v0[2]) + bf2f(v1[2]);
  o0[3] = bf2f(v0[3]) + bf2f(v1[3]);
  o1[0] = bf2f(v0[4]) + bf2f(v1[4]);
  o1[1] = bf2f(v0[5]) + bf2f(v1[5]);
  o1[2] = bf2f(v0[6]) + bf2f(v1[6]);
  o1[3] = bf2f(v0[7]) + bf2f(v1[7]);
  *(f32x4*)(y + (long)t * DD + c) = o0;
  *(f32x4*)(y + (long)t * DD + c + 4) = o1;
}

extern "C" void kernel_launch(void* const* d_in, const int* in_sizes, int n_in,
                              void* d_out, int out_size, void* d_ws, size_t ws_size,
                              hipStream_t stream) {
  const float* x    = (const float*)d_in[0];
  const float* ep   = (const float*)d_in[1];
  const int*   eidx = (const int*)d_in[2];
  const float* w13  = (const float*)d_in[3];
  const float* w2   = (const float*)d_in[4];
  float* y = (float*)d_out;

  char* ws = (char*)d_ws;
  size_t off = 0;
  auto alloc = [&](size_t bytes) {
    char* p = ws + off;
    off = (off + bytes + 255) & ~(size_t)255;
    return p;
  };
  u16* xb     = (u16*)alloc((size_t)TT * DD * 2);
  u16* w13t   = (u16*)alloc((size_t)EE * H2 * DD * 2);
  u16* w2t    = (u16*)alloc((size_t)EE * DD * HH * 2);
  u16* hb     = (u16*)alloc((size_t)PADROWS * HH * 2);
  u16* ye     = (u16*)alloc((size_t)PADROWS * DD * 2);
  char* zbase = ws + off;
  int*   ptok   = (int*)alloc((size_t)PADROWS * 4);
  float* pscale = (float*)alloc((size_t)PADROWS * 4);
  int*   cnt    = (int*)alloc(EE * 4);
  int*   cnt2   = (int*)alloc(EE * 4);
  size_t zbytes = (size_t)((ws + off) - zbase);
  int*   pofs   = (int*)alloc((EE + 1) * 4);
  int*   ppos   = (int*)alloc((size_t)PP * 4);
  (void)ws_size; (void)in_sizes; (void)n_in; (void)out_size;

  // zero routing state (pad rows -> token 0, scale 0)
  hipMemsetAsync(zbase, 0, zbytes, stream);

  cast_x_kernel<<<4096, 256, 0, stream>>>(x, xb);
  dim3 tb(32, 8);
  tcast_kernel<<<dim3(H2 / 32, DD / 32, EE), tb, 0, stream>>>(w13, w13t, DD, H2);
  tcast_kernel<<<dim3(DD / 32, HH / 32, EE), tb, 0, stream>>>(w2, w2t, HH, DD);

  count_kernel<<<PP / 256, 256, 0, stream>>>(eidx, cnt);
  scan_kernel<<<1, 64, 0, stream>>>(cnt, pofs);
  place_kernel<<<PP / 256, 256, 0, stream>>>(eidx, ep, pofs, cnt2, ptok, pscale, ppos);

  gemm1_kernel<<<dim3(MAXTILES, HH / 64), 256, 0, stream>>>(xb, w13t, ptok, pofs, hb);
  gemm2_kernel<<<dim3(MAXTILES, DD / 128), 256, 0, stream>>>(hb, w2t, pscale, pofs, ye);
  combine_kernel<<<4096, 256, 0, stream>>>(ye, ppos, y);
}

// Round 3
// 472.437 us; speedup vs baseline: 1.3325x; 1.1445x over previous
//
#include <hip/hip_runtime.h>
#include <cstdint>
#include <cstddef>

// Problem constants (FusedExperts: E=8 TOPK=2, B=2 S=4096 D=1024 H=2048)
#define TT   8192     // tokens = B*S
#define DD   1024     // model dim
#define HH   2048     // hidden dim
#define H2   4096     // 2*H
#define EE   8        // experts
#define PP   16384    // routed pairs = TT*TOPK
#define PADROWS 17280 // max sum of per-expert 128-padded group sizes = 135*128
#define MAXTILES 135

typedef unsigned short u16;
typedef __attribute__((ext_vector_type(8))) short bf16x8;   // 8 bf16 = 4 VGPR (MFMA A/B frag)
typedef __attribute__((ext_vector_type(8))) unsigned short u16x8;
typedef __attribute__((ext_vector_type(4))) float f32x4;    // MFMA C/D frag

__device__ __forceinline__ u16 f2bf(float f) {
  unsigned int u = __builtin_bit_cast(unsigned int, f);
  u += 0x7fffu + ((u >> 16) & 1u);          // round-to-nearest-even
  return (u16)(u >> 16);
}
__device__ __forceinline__ float bf2f(u16 s) {
  unsigned int u = ((unsigned int)s) << 16;
  return __builtin_bit_cast(float, u);
}

__device__ __forceinline__ void gload_lds16(const u16* g, u16* l) {
  __builtin_amdgcn_global_load_lds(
      (const __attribute__((address_space(1))) void*)g,
      (__attribute__((address_space(3))) void*)l, 16, 0, 0);
}

// ---------------- casts ----------------
__global__ void cast_x_kernel(const float* __restrict__ x, u16* __restrict__ xb) {
  const long i = (long)blockIdx.x * 256 + threadIdx.x;  // one thread -> 8 elems
  const f32x4* s = (const f32x4*)(x + i * 8);
  f32x4 a = s[0], b = s[1];
  u16x8 o;
  o[0]=f2bf(a[0]); o[1]=f2bf(a[1]); o[2]=f2bf(a[2]); o[3]=f2bf(a[3]);
  o[4]=f2bf(b[0]); o[5]=f2bf(b[1]); o[6]=f2bf(b[2]); o[7]=f2bf(b[3]);
  *(u16x8*)(xb + i * 8) = o;
}

// src [E][R][C] f32 -> dst [E][C][R] bf16, vectorized 256B-contiguous writes.
// Tile: 128 src-rows x 32 src-cols. LDS [c][r] = [32][136] u16 (272B row, 16B-mult).
// Grid (C/32, R/128, E), block 256.
__global__ void tcast_kernel(const float* __restrict__ src, u16* __restrict__ dst,
                             int R, int C) {
  __shared__ __align__(16) u16 tile[32][136];
  const long base = (long)blockIdx.z * (long)R * C;
  const int c0 = blockIdx.x * 32, r0 = blockIdx.y * 128;
  const int t = threadIdx.x;
  // phase 1: read 128x32 f32 (coalesced 128B rows), store transposed scalar u16
  {
    const int tx = t & 31;          // col
    const int ty = t >> 5;          // row 0..7 (+8*rr)
#pragma unroll
    for (int rr = 0; rr < 16; ++rr) {
      const int r = ty + rr * 8;
      tile[tx][r] = f2bf(src[base + (long)(r0 + r) * C + c0 + tx]);
    }
  }
  __syncthreads();
  // phase 2: each thread writes u16x8; 16 lanes cover 256B contiguous per dst row
  {
    const int k = t & 15;           // chunk within row: r8 = 8k
    const int cb = t >> 4;          // 0..15
#pragma unroll
    for (int i = 0; i < 2; ++i) {
      const int c = i * 16 + cb;
      u16x8 o = *(const u16x8*)(&tile[c][8 * k]);
      *(u16x8*)(dst + base + (long)(c0 + c) * R + r0 + 8 * k) = o;
    }
  }
}

// ---------------- routing ----------------
__global__ void count_kernel(const int* __restrict__ eidx, int* __restrict__ cnt) {
  int i = blockIdx.x * 256 + threadIdx.x;
  if (i < PP) atomicAdd(&cnt[eidx[i]], 1);
}
__global__ void scan_kernel(const int* __restrict__ cnt, int* __restrict__ pofs) {
  if (threadIdx.x == 0 && blockIdx.x == 0) {
    int run = 0;
    for (int e = 0; e < EE; ++e) { pofs[e] = run; run += ((cnt[e] + 127) >> 7) << 7; }
    pofs[EE] = run;
  }
}
__global__ void place_kernel(const int* __restrict__ eidx, const float* __restrict__ p,
                             const int* __restrict__ pofs, int* __restrict__ cnt2,
                             int* __restrict__ ptok, float* __restrict__ pscale,
                             int* __restrict__ ppos) {
  int i = blockIdx.x * 256 + threadIdx.x;
  if (i < PP) {
    int e = eidx[i];
    int r = atomicAdd(&cnt2[e], 1);
    int pos = pofs[e] + r;
    ptok[pos] = i >> 1;       // token index (TOPK=2)
    pscale[pos] = p[i];
    ppos[i] = pos;
  }
}

// ============ GEMM cores: m97 structure + T2 XOR swizzle + T1 XCD swizzle ============
// LDS tile [128][64] bf16 (128 B rows, 8 slots of 16 B). Data for (row, slot)
// stored at slot' = slot ^ (row&7). global_load_lds writes linearly, so the
// per-lane GLOBAL source is inverse-swizzled (rule #21). 4 waves 2x2, 4x4 frags.
// T1: flat block id -> XCD-contiguous logical (tile, j) so same-expert weight
// slices stay hot in one XCD's L2.

// GEMM1: hb[pos, 0:H] = silu(g)*h where hg = x[tok] @ w13[e]
__global__ __launch_bounds__(256, 2)
void gemm1_kernel(const u16* __restrict__ xb, const u16* __restrict__ w13t,
                  const int* __restrict__ ptok, const int* __restrict__ pofs,
                  u16* __restrict__ hb) {
  __shared__ __align__(16) u16 lds_a[128 * 64];
  __shared__ __align__(16) u16 lds_b[128 * 64];

  // T1 XCD swizzle: nwg = 135*32 = 4320 = 8*540 (exact)
  const int f = blockIdx.y * MAXTILES + blockIdx.x;
  const int wg = (f & 7) * 540 + (f >> 3);
  const int tileIdx = wg % MAXTILES;
  const int j = wg / MAXTILES;                 // h cols [j*64, j*64+64)

  const int ts = tileIdx * 128;
  if (ts >= pofs[EE]) return;
  int e = 0;
#pragma unroll
  for (int i = 1; i < EE; ++i) e += (ts >= pofs[i]) ? 1 : 0;

  const int tid = threadIdx.x;
  const int w = tid >> 6, lane = tid & 63;
  const int wr = w >> 1, wc = w & 1;

  const u16* bbase = w13t + (long)e * ((long)H2 * DD);

  // --- staging setup: 4 rounds each of A and B; 16 B per lane per round ---
  const u16* asrc[4]; const u16* bsrc[4];
  u16* adst[4]; u16* bdst[4];
#pragma unroll
  for (int r = 0; r < 4; ++r) {
    const int L = (r * 4 + w) * 1024 + lane * 16;       // linear LDS byte
    const int row = L >> 7;                              // 128 B per row
    const int slot = ((L >> 4) & 7) ^ (row & 7);         // inverse-swizzled src slot
    asrc[r] = xb + (long)ptok[ts + row] * DD + slot * 8;
    const int gr = (row < 64) ? (j * 64 + row) : (HH + j * 64 + row - 64);
    bsrc[r] = bbase + (long)gr * DD + slot * 8;
    adst[r] = lds_a + (r * 4 + w) * 512;                 // wave-uniform base
    bdst[r] = lds_b + (r * 4 + w) * 512;
  }

  // --- fragment read offsets (u16 units), swizzled ---
  const int rA = wr * 64 + (lane & 15);
  const int sA = lane >> 4;
  const int x7 = lane & 7;
  int aoff[2][4], boff[2][4];
  int rB[4];
  rB[0] = wc * 32 + (lane & 15);
  rB[1] = wc * 32 + 16 + (lane & 15);
  rB[2] = 64 + wc * 32 + (lane & 15);
  rB[3] = 64 + wc * 32 + 16 + (lane & 15);
#pragma unroll
  for (int kk = 0; kk < 2; ++kk) {
    const int sl = ((kk * 4 + sA) ^ x7) * 8;
#pragma unroll
    for (int m = 0; m < 4; ++m) aoff[kk][m] = (rA + m * 16) * 64 + sl;
#pragma unroll
    for (int n = 0; n < 4; ++n) boff[kk][n] = rB[n] * 64 + sl;
  }

  f32x4 acc[4][4];
#pragma unroll
  for (int m = 0; m < 4; ++m)
#pragma unroll
    for (int n = 0; n < 4; ++n) acc[m][n] = (f32x4){0.f, 0.f, 0.f, 0.f};

  for (int k0 = 0; k0 < DD; k0 += 64) {
#pragma unroll
    for (int r = 0; r < 4; ++r) gload_lds16(asrc[r] + k0, adst[r]);
#pragma unroll
    for (int r = 0; r < 4; ++r) gload_lds16(bsrc[r] + k0, bdst[r]);
    __syncthreads();

    bf16x8 af[2][4], bfr[2][4];
#pragma unroll
    for (int kk = 0; kk < 2; ++kk) {
#pragma unroll
      for (int m = 0; m < 4; ++m) af[kk][m] = *(const bf16x8*)(lds_a + aoff[kk][m]);
#pragma unroll
      for (int n = 0; n < 4; ++n) bfr[kk][n] = *(const bf16x8*)(lds_b + boff[kk][n]);
    }
#pragma unroll
    for (int m = 0; m < 4; ++m)
#pragma unroll
      for (int n = 0; n < 4; ++n)
#pragma unroll
        for (int kk = 0; kk < 2; ++kk)
          acc[m][n] = __builtin_amdgcn_mfma_f32_16x16x32_bf16(af[kk][m], bfr[kk][n], acc[m][n], 0, 0, 0);
    __syncthreads();
  }

  // epilogue: silu(g)*h in registers (n-frag pairs (0,2) and (1,3) share cols)
  const int rg = lane >> 4;              // C/D: row = rg*4 + r, col = lane&15
#pragma unroll
  for (int m = 0; m < 4; ++m)
#pragma unroll
    for (int n = 0; n < 2; ++n) {
      const int col = j * 64 + wc * 32 + n * 16 + (lane & 15);
#pragma unroll
      for (int r = 0; r < 4; ++r) {
        const int row = ts + wr * 64 + m * 16 + rg * 4 + r;
        const float h = acc[m][n][r];
        const float g = acc[m][n + 2][r];
        hb[(long)row * HH + col] = f2bf(h * (g / (1.f + __expf(-g))));
      }
    }
}

// GEMM2: ye[pos,:] = pscale[pos] * (hb[pos,:] @ w2t[e]^T), tile 128x128
__global__ __launch_bounds__(256, 2)
void gemm2_kernel(const u16* __restrict__ hb, const u16* __restrict__ w2t,
                  const float* __restrict__ pscale, const int* __restrict__ pofs,
                  u16* __restrict__ ye) {
  __shared__ __align__(16) u16 lds_a[128 * 64];
  __shared__ __align__(16) u16 lds_b[128 * 64];

  // T1 XCD swizzle: nwg = 135*8 = 1080 = 8*135 (exact)
  const int f = blockIdx.y * MAXTILES + blockIdx.x;
  const int wg = (f & 7) * 135 + (f >> 3);
  const int tileIdx = wg % MAXTILES;
  const int j = wg / MAXTILES;                 // out cols [j*128, j*128+128)

  const int ts = tileIdx * 128;
  if (ts >= pofs[EE]) return;
  int e = 0;
#pragma unroll
  for (int i = 1; i < EE; ++i) e += (ts >= pofs[i]) ? 1 : 0;

  const int tid = threadIdx.x;
  const int w = tid >> 6, lane = tid & 63;
  const int wr = w >> 1, wc = w & 1;

  const u16* bbase = w2t + (long)e * ((long)DD * HH);

  const u16* asrc[4]; const u16* bsrc[4];
  u16* adst[4]; u16* bdst[4];
#pragma unroll
  for (int r = 0; r < 4; ++r) {
    const int L = (r * 4 + w) * 1024 + lane * 16;
    const int row = L >> 7;
    const int slot = ((L >> 4) & 7) ^ (row & 7);
    asrc[r] = hb + (long)(ts + row) * HH + slot * 8;
    bsrc[r] = bbase + (long)(j * 128 + row) * HH + slot * 8;
    adst[r] = lds_a + (r * 4 + w) * 512;
    bdst[r] = lds_b + (r * 4 + w) * 512;
  }

  const int rA = wr * 64 + (lane & 15);
  const int sA = lane >> 4;
  const int x7 = lane & 7;
  int aoff[2][4], boff[2][4];
#pragma unroll
  for (int kk = 0; kk < 2; ++kk) {
    const int sl = ((kk * 4 + sA) ^ x7) * 8;
#pragma unroll
    for (int m = 0; m < 4; ++m) aoff[kk][m] = (rA + m * 16) * 64 + sl;
#pragma unroll
    for (int n = 0; n < 4; ++n) boff[kk][n] = (wc * 64 + n * 16 + (lane & 15)) * 64 + sl;
  }

  f32x4 acc[4][4];
#pragma unroll
  for (int m = 0; m < 4; ++m)
#pragma unroll
    for (int n = 0; n < 4; ++n) acc[m][n] = (f32x4){0.f, 0.f, 0.f, 0.f};

  for (int k0 = 0; k0 < HH; k0 += 64) {
#pragma unroll
    for (int r = 0; r < 4; ++r) gload_lds16(asrc[r] + k0, adst[r]);
#pragma unroll
    for (int r = 0; r < 4; ++r) gload_lds16(bsrc[r] + k0, bdst[r]);
    __syncthreads();

    bf16x8 af[2][4], bfr[2][4];
#pragma unroll
    for (int kk = 0; kk < 2; ++kk) {
#pragma unroll
      for (int m = 0; m < 4; ++m) af[kk][m] = *(const bf16x8*)(lds_a + aoff[kk][m]);
#pragma unroll
      for (int n = 0; n < 4; ++n) bfr[kk][n] = *(const bf16x8*)(lds_b + boff[kk][n]);
    }
#pragma unroll
    for (int m = 0; m < 4; ++m)
#pragma unroll
      for (int n = 0; n < 4; ++n)
#pragma unroll
        for (int kk = 0; kk < 2; ++kk)
          acc[m][n] = __builtin_amdgcn_mfma_f32_16x16x32_bf16(af[kk][m], bfr[kk][n], acc[m][n], 0, 0, 0);
    __syncthreads();
  }

  const int rg = lane >> 4;
#pragma unroll
  for (int m = 0; m < 4; ++m)
#pragma unroll
    for (int r = 0; r < 4; ++r) {
      const int row = ts + wr * 64 + m * 16 + rg * 4 + r;
      const float sc = pscale[row];   // 0.0 for pad rows
#pragma unroll
      for (int n = 0; n < 4; ++n) {
        const int col = j * 128 + wc * 64 + n * 16 + (lane & 15);
        ye[(long)row * DD + col] = f2bf(acc[m][n][r] * sc);
      }
    }
}

// ---------------- combine: y[t] = ye[pos0] + ye[pos1] ----------------
__global__ void combine_kernel(const u16* __restrict__ ye, const int* __restrict__ ppos,
                               float* __restrict__ y) {
  const long i = (long)blockIdx.x * 256 + threadIdx.x;  // one thread -> 8 outputs
  const int t = (int)(i >> 7);
  const int c = ((int)i & 127) * 8;
  const int p0 = ppos[t * 2], p1 = ppos[t * 2 + 1];
  u16x8 v0 = *(const u16x8*)(ye + (long)p0 * DD + c);
  u16x8 v1 = *(const u16x8*)(ye + (long)p1 * DD + c);
  f32x4 o0, o1;
  o0[0] = bf2f(v0[0]) + bf2f(v1[0]);
  o0[1] = bf2f(v0[1]) + bf2f(v1[1]);
  o0[2] = bf2f(v0[2]) + bf2f(v1[2]);
  o0[3] = bf2f(v0[3]) + bf2f(v1[3]);
  o1[0] = bf2f(v0[4]) + bf2f(v1[4]);
  o1[1] = bf2f(v0[5]) + bf2f(v1[5]);
  o1[2] = bf2f(v0[6]) + bf2f(v1[6]);
  o1[3] = bf2f(v0[7]) + bf2f(v1[7]);
  *(f32x4*)(y + (long)t * DD + c) = o0;
  *(f32x4*)(y + (long)t * DD + c + 4) = o1;
}

extern "C" void kernel_launch(void* const* d_in, const int* in_sizes, int n_in,
                              void* d_out, int out_size, void* d_ws, size_t ws_size,
                              hipStream_t stream) {
  const float* x    = (const float*)d_in[0];
  const float* ep   = (const float*)d_in[1];
  const int*   eidx = (const int*)d_in[2];
  const float* w13  = (const float*)d_in[3];
  const float* w2   = (const float*)d_in[4];
  float* y = (float*)d_out;

  char* ws = (char*)d_ws;
  size_t off = 0;
  auto alloc = [&](size_t bytes) {
    char* p = ws + off;
    off = (off + bytes + 255) & ~(size_t)255;
    return p;
  };
  u16* xb     = (u16*)alloc((size_t)TT * DD * 2);
  u16* w13t   = (u16*)alloc((size_t)EE * H2 * DD * 2);
  u16* w2t    = (u16*)alloc((size_t)EE * DD * HH * 2);
  u16* hb     = (u16*)alloc((size_t)PADROWS * HH * 2);
  u16* ye     = (u16*)alloc((size_t)PADROWS * DD * 2);
  char* zbase = ws + off;
  int*   ptok   = (int*)alloc((size_t)PADROWS * 4);
  float* pscale = (float*)alloc((size_t)PADROWS * 4);
  int*   cnt    = (int*)alloc(EE * 4);
  int*   cnt2   = (int*)alloc(EE * 4);
  size_t zbytes = (size_t)((ws + off) - zbase);
  int*   pofs   = (int*)alloc((EE + 1) * 4);
  int*   ppos   = (int*)alloc((size_t)PP * 4);
  (void)ws_size; (void)in_sizes; (void)n_in; (void)out_size;

  // zero routing state (pad rows -> token 0, scale 0)
  hipMemsetAsync(zbase, 0, zbytes, stream);

  cast_x_kernel<<<4096, 256, 0, stream>>>(x, xb);
  // w13 [E][1024][4096] -> w13t [E][4096][1024]
  tcast_kernel<<<dim3(H2 / 32, DD / 128, EE), 256, 0, stream>>>(w13, w13t, DD, H2);
  // w2 [E][2048][1024] -> w2t [E][1024][2048]
  tcast_kernel<<<dim3(DD / 32, HH / 128, EE), 256, 0, stream>>>(w2, w2t, HH, DD);

  count_kernel<<<PP / 256, 256, 0, stream>>>(eidx, cnt);
  scan_kernel<<<1, 64, 0, stream>>>(cnt, pofs);
  place_kernel<<<PP / 256, 256, 0, stream>>>(eidx, ep, pofs, cnt2, ptok, pscale, ppos);

  gemm1_kernel<<<dim3(MAXTILES, HH / 64), 256, 0, stream>>>(xb, w13t, ptok, pofs, hb);
  gemm2_kernel<<<dim3(MAXTILES, DD / 128), 256, 0, stream>>>(hb, w2t, pscale, pofs, ye);
  combine_kernel<<<4096, 256, 0, stream>>>(ye, ppos, y);
}